// Round 3
// baseline (195.989 us; speedup 1.0000x reference)
//
#include <hip/hip_runtime.h>
#include <hip/hip_bf16.h>

#define NUM_USER 100000
#define K_NEIGH 32
#define DIM 64          // 16 float4-chunks per row

typedef float floatx4 __attribute__((ext_vector_type(4)));

__global__ __launch_bounds__(256) void user_graph_gather_kernel(
    const floatx4* __restrict__ features4,  // [NUM_USER][16] 16B chunks
    const int*     __restrict__ graph,      // [NUM_USER][32]
    const float*   __restrict__ matrix,     // [NUM_USER][32]
    floatx4*       __restrict__ out4) {     // [NUM_USER][16]
  int t  = blockIdx.x * blockDim.x + threadIdx.x;
  int u  = t >> 4;          // 16 lanes per user, 4 users per wave
  int d4 = t & 15;          // which 16B chunk of the 256B row
  if (u >= NUM_USER) return;

  const int*   g = graph  + u * K_NEIGH;
  const float* w = matrix + u * K_NEIGH;

  floatx4 acc = (floatx4)(0.f, 0.f, 0.f, 0.f);
#pragma unroll
  for (int k = 0; k < K_NEIGH; ++k) {
    // streamed-once data: nontemporal so it doesn't evict feature rows in L2
    int   idx = __builtin_nontemporal_load(g + k);   // uniform across 16 lanes
    float wk  = __builtin_nontemporal_load(w + k);
    floatx4 f = features4[idx * 16 + d4];            // 16 lanes x 16B = full 256B row
    acc += wk * f;
  }
  __builtin_nontemporal_store(acc, out4 + u * 16 + d4);  // write-once output
}

extern "C" void kernel_launch(void* const* d_in, const int* in_sizes, int n_in,
                              void* d_out, int out_size, void* d_ws, size_t ws_size,
                              hipStream_t stream) {
  const floatx4* features = (const floatx4*)d_in[0];
  const int*     graph    = (const int*)d_in[1];
  const float*   matrix   = (const float*)d_in[2];
  floatx4*       out      = (floatx4*)d_out;

  const int total = NUM_USER * 16;            // 1,600,000 threads
  const int block = 256;
  const int grid  = (total + block - 1) / block;  // 6250 blocks
  user_graph_gather_kernel<<<grid, block, 0, stream>>>(features, graph, matrix, out);
}

// Round 4
// 138.230 us; speedup vs baseline: 1.4178x; 1.4178x over previous
//
#include <hip/hip_runtime.h>
#include <hip/hip_bf16.h>

#define NUM_USER 100000
#define K_NEIGH 32
#define DIM 64

typedef float floatx2 __attribute__((ext_vector_type(2)));

// Kernel 1: compress fp32 features -> packed bf16x2 table in d_ws.
// table[u*32 + j] packs dims {2j (low 16), 2j+1 (high 16)} with RNE rounding.
__global__ __launch_bounds__(256) void convert_bf16_kernel(
    const floatx2* __restrict__ feat2,   // 3.2M float2
    unsigned int*  __restrict__ table) { // 3.2M packed bf16x2
  int i = blockIdx.x * blockDim.x + threadIdx.x;
  if (i >= NUM_USER * DIM / 2) return;
  floatx2 f = feat2[i];
  unsigned int ux = __float_as_uint(f.x);
  unsigned int uy = __float_as_uint(f.y);
  // round-to-nearest-even to bf16
  unsigned int bx = (ux + 0x7fffu + ((ux >> 16) & 1u)) >> 16;
  unsigned int by = (uy + 0x7fffu + ((uy >> 16) & 1u)) >> 16;
  table[i] = bx | (by << 16);
}

// Kernel 2: gather+weighted-sum from the bf16 table.
// 32 lanes per user (2 users/wave); each lane owns dims {2*d2, 2*d2+1}.
__global__ __launch_bounds__(256) void user_graph_gather_bf16_kernel(
    const unsigned int* __restrict__ table,   // [NUM_USER][32] bf16x2
    const int*          __restrict__ graph,   // [NUM_USER][32]
    const float*        __restrict__ matrix,  // [NUM_USER][32]
    floatx2*            __restrict__ out2) {  // [NUM_USER][32] float2
  int t  = blockIdx.x * blockDim.x + threadIdx.x;
  int u  = t >> 5;
  int d2 = t & 31;
  if (u >= NUM_USER) return;

  const int*   g = graph  + u * K_NEIGH;
  const float* w = matrix + u * K_NEIGH;

  float acc0 = 0.f, acc1 = 0.f;
#pragma unroll
  for (int k = 0; k < K_NEIGH; ++k) {
    int   idx = g[k];                          // uniform per 32-lane group
    float wk  = w[k];
    unsigned int p = table[idx * 32 + d2];     // 32 lanes x 4B = one 128B line
    float flo = __uint_as_float(p << 16);          // dim 2*d2
    float fhi = __uint_as_float(p & 0xffff0000u);  // dim 2*d2+1
    acc0 += wk * flo;
    acc1 += wk * fhi;
  }
  floatx2 r; r.x = acc0; r.y = acc1;
  out2[u * 32 + d2] = r;                       // 8B/lane coalesced store
}

// Fallback (no ws space): round-1 fp32 gather, known-good 104us.
__global__ __launch_bounds__(256) void user_graph_gather_f32_kernel(
    const float* __restrict__ features,
    const int*   __restrict__ graph,
    const float* __restrict__ matrix,
    float*       __restrict__ out) {
  int t = blockIdx.x * blockDim.x + threadIdx.x;
  int u = t >> 6;
  int d = t & 63;
  if (u >= NUM_USER) return;
  const int*   g = graph  + (size_t)u * K_NEIGH;
  const float* w = matrix + (size_t)u * K_NEIGH;
  float acc = 0.f;
#pragma unroll
  for (int k = 0; k < K_NEIGH; ++k)
    acc += w[k] * features[(size_t)g[k] * DIM + d];
  out[(size_t)u * DIM + d] = acc;
}

extern "C" void kernel_launch(void* const* d_in, const int* in_sizes, int n_in,
                              void* d_out, int out_size, void* d_ws, size_t ws_size,
                              hipStream_t stream) {
  const float* features = (const float*)d_in[0];
  const int*   graph    = (const int*)d_in[1];
  const float* matrix   = (const float*)d_in[2];

  const size_t table_bytes = (size_t)NUM_USER * DIM * 2;  // 12.8 MB bf16
  if (ws_size >= table_bytes) {
    unsigned int* table = (unsigned int*)d_ws;
    const int n_pack = NUM_USER * DIM / 2;   // 3.2M
    convert_bf16_kernel<<<(n_pack + 255) / 256, 256, 0, stream>>>(
        (const floatx2*)features, table);
    const int total = NUM_USER * 32;         // 3.2M threads
    user_graph_gather_bf16_kernel<<<(total + 255) / 256, 256, 0, stream>>>(
        table, graph, matrix, (floatx2*)d_out);
  } else {
    const int total = NUM_USER * DIM;
    user_graph_gather_f32_kernel<<<(total + 255) / 256, 256, 0, stream>>>(
        features, graph, matrix, (float*)d_out);
  }
}